// Round 2
// baseline (180.209 us; speedup 1.0000x reference)
//
#include <hip/hip_runtime.h>

// Problem constants (hard-coded from reference: SHAPES fixed at trace time)
// Level l: W=48>>l, Hgrid=128>>l, start = 8192 - (8192 >> (2*l)); LEN=8160.

#define LEN 8160
#define NPACK8 (1280 * 256 / 8)      // 40,960 (8-elem pack units)

#define AS1 __attribute__((address_space(1)))
#define AS3 __attribute__((address_space(3)))

typedef __attribute__((ext_vector_type(8))) short bf16x8;
typedef __attribute__((ext_vector_type(8))) unsigned short u16x8;
typedef __attribute__((ext_vector_type(4))) float f32x4;

__device__ __forceinline__ unsigned short rne_bf16(float v)
{
    unsigned u = __float_as_uint(v);
    return (unsigned short)((u + 0x7FFFu + ((u >> 16) & 1u)) >> 16);
}

// Round-to-nearest-even split of fp32 into hi+lo bf16 (bf16x3 GEMM trick).
__device__ __forceinline__ void split_bf16(float v, unsigned short* hi, unsigned short* lo)
{
    unsigned u = __float_as_uint(v);
    unsigned r = (u + 0x7FFFu + ((u >> 16) & 1u)) & 0xFFFF0000u;
    float hif = __uint_as_float(r);
    float lof = v - hif;
    unsigned ul = __float_as_uint(lof);
    unsigned rl = (ul + 0x7FFFu + ((ul >> 16) & 1u)) >> 16;
    *hi = (unsigned short)(r >> 16);
    *lo = (unsigned short)rl;
}

__device__ __forceinline__ float bf2f(unsigned short s)
{
    return __uint_as_float(((unsigned)s) << 16);
}

// Inline split of 8 consecutive f32 A elements into hi/lo bf16x8 fragments.
// Works for global or LDS-backed pointers (generic addressing).
__device__ __forceinline__ void splitA8(const float* a, bf16x8* hi, bf16x8* lo)
{
    float4 x = *(const float4*)a;
    float4 y = *(const float4*)(a + 4);
    unsigned short h[8], l[8];
    split_bf16(x.x, &h[0], &l[0]); split_bf16(x.y, &h[1], &l[1]);
    split_bf16(x.z, &h[2], &l[2]); split_bf16(x.w, &h[3], &l[3]);
    split_bf16(y.x, &h[4], &l[4]); split_bf16(y.y, &h[5], &l[5]);
    split_bf16(y.z, &h[6], &l[6]); split_bf16(y.w, &h[7], &l[7]);
    bf16x8 hv, lv;
    #pragma unroll
    for (int i = 0; i < 8; i++) { hv[i] = (short)h[i]; lv[i] = (short)l[i]; }
    *hi = hv; *lo = lv;
}

// ---------------------------------------------------------------------------
// prep: pack all weights transposed (B^T[n][k]) into hi/lo bf16 planes +
// concat bias. Row space: [0,256)=WvT [256,1024)=BcatT [1024,1280)=WoT.
// ---------------------------------------------------------------------------
__global__ __launch_bounds__(256) void prep_kernel(
    const float* __restrict__ Ws, const float* __restrict__ bs,
    const float* __restrict__ Wa, const float* __restrict__ ba,
    const float* __restrict__ Wts, const float* __restrict__ bts,
    const float* __restrict__ Wta, const float* __restrict__ bta,
    const float* __restrict__ Wv, const float* __restrict__ Wo,
    unsigned short* __restrict__ Whi, unsigned short* __restrict__ Wlo,
    float* __restrict__ bcat)
{
    int idx = blockIdx.x * 256 + threadIdx.x;
    if (idx < NPACK8) {
        int n = idx >> 5;
        int k0 = (idx & 31) << 3;
        unsigned short h[8], l[8];
        #pragma unroll
        for (int t = 0; t < 8; t++) {
            int k = k0 + t;
            float v;
            if (n < 256) v = Wv[k * 256 + n];
            else if (n < 1024) {
                int j = n - 256;
                if (j < 256)      v = Ws [k * 256 + j];
                else if (j < 384) v = Wa [k * 128 + (j - 256)];
                else if (j < 640) v = Wts[k * 256 + (j - 384)];
                else              v = Wta[k * 128 + (j - 640)];
            } else v = Wo[k * 256 + (n - 1024)];
            split_bf16(v, &h[t], &l[t]);
        }
        uint4 hv, lv;
        hv.x = h[0] | ((unsigned)h[1] << 16); hv.y = h[2] | ((unsigned)h[3] << 16);
        hv.z = h[4] | ((unsigned)h[5] << 16); hv.w = h[6] | ((unsigned)h[7] << 16);
        lv.x = l[0] | ((unsigned)l[1] << 16); lv.y = l[2] | ((unsigned)l[3] << 16);
        lv.z = l[4] | ((unsigned)l[5] << 16); lv.w = l[6] | ((unsigned)l[7] << 16);
        *(uint4*)(Whi + n * 256 + k0) = hv;
        *(uint4*)(Wlo + n * 256 + k0) = lv;
    } else if (idx < NPACK8 + 768) {
        int j = idx - NPACK8;
        float v;
        if (j < 256)      v = bs[j];
        else if (j < 384) v = ba[j - 256];
        else if (j < 640) v = bts[j - 384];
        else              v = bta[j - 640];
        bcat[j] = v;
    }
}

// ---------------------------------------------------------------------------
// bf16x3 MFMA GEMM, dual problem-set, A read as f32 + inline register split.
// Tile 128(M)x64(N), 256 thr = 4 waves, wave owns 32 rows (2 x 16-row
// subtiles). K=256 in 2 chunks of 128; B (hi+lo planes) async-staged per
// chunk into frag-order LDS (32 KB) via width-16 global_load_lds (LDS dest
// linear in lane order; permutation rides on the per-lane GLOBAL address).
// mode: 0 = f32 row-major store; 1 = bf16 store into (head,pos,32ch) planes.
// ---------------------------------------------------------------------------
__global__ __launch_bounds__(256) void gemm_mfma_dual(
    const float* __restrict__ A0,
    const unsigned short* __restrict__ B0hi, const unsigned short* __restrict__ B0lo,
    const float* __restrict__ bias0, void* __restrict__ C0, int N0, int mode0, int nbx0,
    const float* __restrict__ A1,
    const unsigned short* __restrict__ B1hi, const unsigned short* __restrict__ B1lo,
    const float* __restrict__ bias1, void* __restrict__ C1, int N1, int mode1)
{
    // frag-order LDS per chunk: [plane][kt(4)][nt(4)][lane(64)][8 bf16] = 32 KB
    __shared__ __align__(16) unsigned short Bf[2 * 4 * 4 * 64 * 8];
    const int tid = threadIdx.x;
    const int wave = tid >> 6, lane = tid & 63;
    int bx = blockIdx.x;
    const int by = blockIdx.y;

    const float* A;
    const unsigned short *Bhi, *Blo;
    const float* bias; void* C; int N, mode;
    if (bx < nbx0) {
        A = A0; Bhi = B0hi; Blo = B0lo;
        bias = bias0; C = C0; N = N0; mode = mode0;
    } else {
        bx -= nbx0;
        A = A1; Bhi = B1hi; Blo = B1lo;
        bias = bias1; C = C1; N = N1; mode = mode1;
    }

    const int lm = lane & 15;     // m within 16-tile / C column
    const int kq = lane >> 4;     // k-quad (0..3)
    const int m0 = by * 128 + wave * 32 + lm;
    const int ra = min(m0, LEN - 1);            // clamped A rows (loads in-bounds)
    const int rb = min(m0 + 16, LEN - 1);
    const float* aP0 = A + (size_t)ra * 256 + kq * 8;
    const float* aP1 = A + (size_t)rb * 256 + kq * 8;

    f32x4 acc[2][4] = {};
    #pragma unroll
    for (int chunk = 0; chunk < 2; chunk++) {
        // async-stage chunk's B tile (both planes): 2048 slots x 16 B.
        // slot f = g*64 + lane, g = t*4 + wave encodes (pl,kt,nt).
        #pragma unroll
        for (int t = 0; t < 8; t++) {
            const int g  = t * 4 + wave;
            const int nt = g & 3, kt = (g >> 2) & 3, pl = g >> 4;
            const unsigned short* src = (pl ? Blo : Bhi)
                + (size_t)(bx * 64 + nt * 16 + (lane & 15)) * 256
                + chunk * 128 + kt * 32 + (lane >> 4) * 8;
            __builtin_amdgcn_global_load_lds(
                (AS1 void*)(uintptr_t)src,
                (AS3 void*)&Bf[(size_t)g * 64 * 8],
                16, 0, 0);
        }
        asm volatile("s_waitcnt vmcnt(0)" ::: "memory");
        __syncthreads();
        #pragma unroll
        for (int kt = 0; kt < 4; kt++) {
            const int ko = chunk * 128 + kt * 32;
            bf16x8 ah0, al0, ah1, al1;
            splitA8(aP0 + ko, &ah0, &al0);
            splitA8(aP1 + ko, &ah1, &al1);
            #pragma unroll
            for (int nt = 0; nt < 4; nt++) {
                const int fb = (kt * 4 + nt) * 64 + lane;
                bf16x8 bh = *(const bf16x8*)(&Bf[(size_t)fb * 8]);
                bf16x8 bl = *(const bf16x8*)(&Bf[(size_t)(fb + 1024) * 8]);
                acc[0][nt] = __builtin_amdgcn_mfma_f32_16x16x32_bf16(ah0, bh, acc[0][nt], 0, 0, 0);
                acc[0][nt] = __builtin_amdgcn_mfma_f32_16x16x32_bf16(ah0, bl, acc[0][nt], 0, 0, 0);
                acc[0][nt] = __builtin_amdgcn_mfma_f32_16x16x32_bf16(al0, bh, acc[0][nt], 0, 0, 0);
                acc[1][nt] = __builtin_amdgcn_mfma_f32_16x16x32_bf16(ah1, bh, acc[1][nt], 0, 0, 0);
                acc[1][nt] = __builtin_amdgcn_mfma_f32_16x16x32_bf16(ah1, bl, acc[1][nt], 0, 0, 0);
                acc[1][nt] = __builtin_amdgcn_mfma_f32_16x16x32_bf16(al1, bh, acc[1][nt], 0, 0, 0);
            }
        }
        __syncthreads();
    }

    // C/D layout (verified m89/m91): col = lane&15, row = (lane>>4)*4 + reg
    const int col = bx * 64 + lm;
    #pragma unroll
    for (int sub = 0; sub < 2; sub++) {
        const int row0 = by * 128 + wave * 32 + sub * 16 + kq * 4;
        #pragma unroll
        for (int nt = 0; nt < 4; nt++) {
            int c = col + nt * 16;
            float bb = bias[c];
            #pragma unroll
            for (int r = 0; r < 4; r++) {
                int row = row0 + r;
                if (row < LEN) {
                    float v = acc[sub][nt][r] + bb;
                    if (mode) {
                        // value plane layout: head = c>>5, ch = c&31
                        ((unsigned short*)C)[(size_t)(c >> 5) * 8192 * 32
                                             + (size_t)row * 32 + (c & 31)] = rne_bf16(v);
                    } else {
                        ((float*)C)[(size_t)row * N + c] = v;
                    }
                }
            }
        }
    }
}

// ---------------------------------------------------------------------------
// FUSED deformable sampling + output projection.
// 512 threads = 2 teams x (8 heads x 32 lanes); 16 queries per block
// (510 blocks, 8160 = 510*16 exact). Each team processes 8 queries
// sequentially; the attention row (256 f32) lands in LDS. No barriers in
// the sampling loop: s_row/s_w are written and read by the SAME 32-lane
// half-wave (wave program order + lgkmcnt suffice). One __syncthreads,
// then an M=16 MFMA mini-GEMM (attn_s @ WoT, bf16x3) writes `out` directly.
// Bit-identical to the unfused path: same split_bf16, same MFMA order
// (ah*bh, ah*bl, al*bh), bias added after.
// ---------------------------------------------------------------------------
__global__ __launch_bounds__(512, 4) void fused_sample_out(
    const unsigned short* __restrict__ value,  // (8, 8192, 32) bf16 planes
    const float* __restrict__ proj,    // (8160, 768)
    const float* __restrict__ refp,    // (8160, 4, 2)
    const float* __restrict__ toff,    // (8160, 4, 2, 2)
    const unsigned short* __restrict__ WoThi,  // (256, 256) = WoT hi plane
    const unsigned short* __restrict__ WoTlo,  // (256, 256) = WoT lo plane
    const float* __restrict__ bo,      // (256,)
    float* __restrict__ out)           // (8160, 256) f32
{
    const int team = threadIdx.x >> 8;        // 0..1
    const int head = (threadIdx.x >> 5) & 7;  // 0..7
    const int lane = threadIdx.x & 31;
    const int q0 = blockIdx.x * 16;

    __shared__ int2   s_row[2][8][32];
    __shared__ float4 s_w[2][8][32];
    // +4 pad: keeps rows 16B-aligned (stride 1040 B) and banks <=2-way.
    __shared__ float  attn_s[16][260];

    const int pt4  = lane >> 3;        // 0..3
    const int half = (lane >> 2) & 1;  // x-half within the 128B pair
    const int cg   = lane & 3;         // 8-channel group
    const char* vbase = (const char*)value + head * (8192 * 64) + half * 64 + cg * 16;

    for (int qi = 0; qi < 8; qi++) {
        const int q = q0 + team * 8 + qi;
        const float* p = proj + (size_t)q * 768;

        // ---- phase 1: per-point location, joint softmax, bilinear setup ----
        {
            const int i = lane;
            float logit, ox, oy, rx, ry;
            int l;
            if (i < 16) {
                l = i >> 2; int pt2 = i & 3;
                logit = p[256 + head * 16 + i];
                ox = p[head * 32 + l * 8 + pt2 * 2 + 0];
                oy = p[head * 32 + l * 8 + pt2 * 2 + 1];
                rx = refp[q * 8 + l * 2 + 0];
                ry = refp[q * 8 + l * 2 + 1];
            } else {
                int j = i - 16; l = j >> 2;
                int tp = j & 3, tw = tp >> 1, nt = tp & 1;
                logit = p[640 + head * 16 + j];
                ox = p[384 + head * 32 + l * 8 + tw * 4 + nt * 2 + 0];
                oy = p[384 + head * 32 + l * 8 + tw * 4 + nt * 2 + 1];
                rx = refp[q * 8 + l * 2 + 0] + toff[q * 16 + l * 4 + tw * 2 + 0];
                ry = refp[q * 8 + l * 2 + 1] + toff[q * 16 + l * 4 + tw * 2 + 1];
            }
            const int Wl = 48 >> l;
            const int Hgl = 128 >> l;
            const int st = 8192 - (8192 >> (2 * l));
            const float fW = (float)Wl, fHg = (float)Hgl;
            float x = (rx + ox / fW) * fW - 0.5f;
            float y = (ry + oy / fHg) * fHg - 0.5f;

            float mx = logit;
            #pragma unroll
            for (int off = 16; off > 0; off >>= 1)
                mx = fmaxf(mx, __shfl_xor(mx, off, 32));
            float e = expf(logit - mx);
            float s = e;
            #pragma unroll
            for (int off = 16; off > 0; off >>= 1)
                s += __shfl_xor(s, off, 32);
            float w = e / s;

            float fx = floorf(x), fy = floorf(y);
            float wx = x - fx, wy = y - fy;
            int x0 = (int)fx, y0 = (int)fy;
            int x1 = x0 + 1, y1 = y0 + 1;
            float mx0 = ((unsigned)x0 < (unsigned)Wl) ? 1.f : 0.f;
            float mx1 = ((unsigned)x1 < (unsigned)Wl) ? 1.f : 0.f;
            float my0 = ((unsigned)y0 < (unsigned)Hgl) ? 1.f : 0.f;
            float my1 = ((unsigned)y1 < (unsigned)Hgl) ? 1.f : 0.f;
            int cx0 = min(max(x0, 0), Wl - 1), cx1 = min(max(x1, 0), Wl - 1);
            int cy0 = min(max(y0, 0), Hgl - 1), cy1 = min(max(y1, 0), Hgl - 1);
            int xb = min(max(x0, 0), Wl - 2);
            float sx0 = 1.f - wx, sy0 = 1.f - wy;
            float aL = (cx0 == xb     ? sx0 * mx0 : 0.f) + (cx1 == xb     ? wx * mx1 : 0.f);
            float aR = (cx0 == xb + 1 ? sx0 * mx0 : 0.f) + (cx1 == xb + 1 ? wx * mx1 : 0.f);
            float by0 = sy0 * my0, by1 = wy * my1;
            int2 rr;   // BYTE offsets within a head plane (64 B per position)
            rr.x = (st + cy0 * Wl + xb) * 64;
            rr.y = (st + cy1 * Wl + xb) * 64;
            float4 ww;
            ww.x = w * aL * by0;
            ww.y = w * aR * by0;
            ww.z = w * aL * by1;
            ww.w = w * aR * by1;
            s_row[team][head][lane] = rr;
            s_w[team][head][lane] = ww;
        }
        // no barrier: half-wave locality (see header comment)

        // ---- phase 2: x-pair gathers, 4 points in flight per 32-lane group ----
        float acc[8] = {0.f, 0.f, 0.f, 0.f, 0.f, 0.f, 0.f, 0.f};
        #pragma unroll
        for (int i = 0; i < 8; i++) {
            int pidx = (i << 2) | pt4;
            int2 rr = s_row[team][head][pidx];
            float4 ww = s_w[team][head][pidx];
            u16x8 v0 = *(const u16x8*)(vbase + rr.x);
            u16x8 v1 = *(const u16x8*)(vbase + rr.y);
            float w0 = half ? ww.y : ww.x;
            float w1 = half ? ww.w : ww.z;
            #pragma unroll
            for (int j = 0; j < 8; j++) {
                acc[j] = fmaf(w0, bf2f(v0[j]), acc[j]);
                acc[j] = fmaf(w1, bf2f(v1[j]), acc[j]);
            }
        }
        // butterfly: xor4 merges x-halves, xor8/16 merge the 4 points
        #pragma unroll
        for (int off = 4; off <= 16; off <<= 1)
            #pragma unroll
            for (int j = 0; j < 8; j++)
                acc[j] += __shfl_xor(acc[j], off, 32);

        if (lane < 4) {
            float* dst = &attn_s[team * 8 + qi][head * 32 + cg * 8];
            *(float4*)dst       = make_float4(acc[0], acc[1], acc[2], acc[3]);
            *(float4*)(dst + 4) = make_float4(acc[4], acc[5], acc[6], acc[7]);
        }
    }
    __syncthreads();

    // ---- mini-GEMM: out[q0..q0+16) = attn_s @ Wo + bo (bf16x3) ----
    const int wv = threadIdx.x >> 6;   // 0..7, wave owns 32 output cols
    const int l  = threadIdx.x & 63;
    const int lm = l & 15, kq = l >> 4;
    f32x4 acc2[2] = {};
    #pragma unroll
    for (int ks = 0; ks < 8; ks++) {
        bf16x8 ah, al;
        splitA8(&attn_s[lm][ks * 32 + kq * 8], &ah, &al);
        #pragma unroll
        for (int nt = 0; nt < 2; nt++) {
            const int col = wv * 32 + nt * 16 + lm;
            const size_t bofs = (size_t)col * 256 + ks * 32 + kq * 8;
            bf16x8 bh = *(const bf16x8*)(WoThi + bofs);
            bf16x8 bl = *(const bf16x8*)(WoTlo + bofs);
            acc2[nt] = __builtin_amdgcn_mfma_f32_16x16x32_bf16(ah, bh, acc2[nt], 0, 0, 0);
            acc2[nt] = __builtin_amdgcn_mfma_f32_16x16x32_bf16(ah, bl, acc2[nt], 0, 0, 0);
            acc2[nt] = __builtin_amdgcn_mfma_f32_16x16x32_bf16(al, bh, acc2[nt], 0, 0, 0);
        }
    }
    // C/D layout: col = lane&15, row = (lane>>4)*4 + reg; rows = queries
    #pragma unroll
    for (int nt = 0; nt < 2; nt++) {
        const int col = wv * 32 + nt * 16 + lm;
        const float bb = bo[col];
        #pragma unroll
        for (int r = 0; r < 4; r++) {
            const int row = kq * 4 + r;
            out[(size_t)(q0 + row) * 256 + col] = acc2[nt][r] + bb;
        }
    }
}

// ---------------------------------------------------------------------------
extern "C" void kernel_launch(void* const* d_in, const int* in_sizes, int n_in,
                              void* d_out, int out_size, void* d_ws, size_t ws_size,
                              hipStream_t stream)
{
    const float* query = (const float*)d_in[0];
    const float* refp  = (const float*)d_in[1];
    const float* toff  = (const float*)d_in[2];
    const float* inpf  = (const float*)d_in[3];
    const float* Wv  = (const float*)d_in[6];
    const float* bv  = (const float*)d_in[7];
    const float* Ws_ = (const float*)d_in[8];
    const float* bs_ = (const float*)d_in[9];
    const float* Wa  = (const float*)d_in[10];
    const float* ba  = (const float*)d_in[11];
    const float* Wts = (const float*)d_in[12];
    const float* bts = (const float*)d_in[13];
    const float* Wta = (const float*)d_in[14];
    const float* bta = (const float*)d_in[15];
    const float* Wo  = (const float*)d_in[16];
    const float* bo  = (const float*)d_in[17];
    float* out = (float*)d_out;

    // workspace layout (~31 MB)
    unsigned short* value_bf = (unsigned short*)d_ws;          // 8 x 8192 x 32 bf16 planes
    float* proj = (float*)(value_bf + (size_t)8 * 8192 * 32);  // 8160*768 f32
    unsigned short* Whi = (unsigned short*)(proj + (size_t)LEN * 768);  // 1280*256
    unsigned short* Wlo = Whi + 1280 * 256;
    float* bcat = (float*)(Wlo + 1280 * 256);                  // 768

    prep_kernel<<<164, 256, 0, stream>>>(Ws_, bs_, Wa, ba, Wts, bts, Wta, bta,
                                         Wv, Wo, Whi, Wlo, bcat);
    // value(bf16 planes) = inpf @ Wv + bv (bx 0..3) ||
    // proj(f32) = query @ Bcat + bcat (bx 4..15); grid (16, 64) = 1024 blocks
    gemm_mfma_dual<<<dim3(16, 64), 256, 0, stream>>>(
        inpf, Whi, Wlo, bv, value_bf, 256, 1, 4,
        query, Whi + 256 * 256, Wlo + 256 * 256, bcat, proj, 768, 0);
    // fused deformable attention core + output projection -> out
    fused_sample_out<<<510, 512, 0, stream>>>(
        value_bf, proj, refp, toff,
        Whi + 1024 * 256, Wlo + 1024 * 256, bo, out);
}

// Round 3
// 169.432 us; speedup vs baseline: 1.0636x; 1.0636x over previous
//
#include <hip/hip_runtime.h>

// Problem constants (hard-coded from reference: SHAPES fixed at trace time)
// Level l: W=48>>l, Hgrid=128>>l, start = 8192 - (8192 >> (2*l)); LEN=8160.

#define LEN 8160
#define NPACK8 (1280 * 256 / 8)      // 40,960 (8-elem pack units)

#define AS1 __attribute__((address_space(1)))
#define AS3 __attribute__((address_space(3)))

typedef __attribute__((ext_vector_type(8))) short bf16x8;
typedef __attribute__((ext_vector_type(8))) unsigned short u16x8;
typedef __attribute__((ext_vector_type(4))) float f32x4;
typedef __attribute__((ext_vector_type(2))) float f32x2;

__device__ __forceinline__ unsigned short rne_bf16(float v)
{
    unsigned u = __float_as_uint(v);
    return (unsigned short)((u + 0x7FFFu + ((u >> 16) & 1u)) >> 16);
}

// Round-to-nearest-even split of fp32 into hi+lo bf16 (bf16x3 GEMM trick).
__device__ __forceinline__ void split_bf16(float v, unsigned short* hi, unsigned short* lo)
{
    unsigned u = __float_as_uint(v);
    unsigned r = (u + 0x7FFFu + ((u >> 16) & 1u)) & 0xFFFF0000u;
    float hif = __uint_as_float(r);
    float lof = v - hif;
    unsigned ul = __float_as_uint(lof);
    unsigned rl = (ul + 0x7FFFu + ((ul >> 16) & 1u)) >> 16;
    *hi = (unsigned short)(r >> 16);
    *lo = (unsigned short)rl;
}

__device__ __forceinline__ float bf2f(unsigned short s)
{
    return __uint_as_float(((unsigned)s) << 16);
}

// Inline split of 8 consecutive f32 A elements into hi/lo bf16x8 fragments.
__device__ __forceinline__ void splitA8(const float* a, bf16x8* hi, bf16x8* lo)
{
    float4 x = *(const float4*)a;
    float4 y = *(const float4*)(a + 4);
    unsigned short h[8], l[8];
    split_bf16(x.x, &h[0], &l[0]); split_bf16(x.y, &h[1], &l[1]);
    split_bf16(x.z, &h[2], &l[2]); split_bf16(x.w, &h[3], &l[3]);
    split_bf16(y.x, &h[4], &l[4]); split_bf16(y.y, &h[5], &l[5]);
    split_bf16(y.z, &h[6], &l[6]); split_bf16(y.w, &h[7], &l[7]);
    bf16x8 hv, lv;
    #pragma unroll
    for (int i = 0; i < 8; i++) { hv[i] = (short)h[i]; lv[i] = (short)l[i]; }
    *hi = hv; *lo = lv;
}

// ---------------------------------------------------------------------------
// prep: pack all weights transposed (B^T[n][k]) into hi/lo bf16 planes +
// concat bias. Row space: [0,256)=WvT [256,1024)=BcatT [1024,1280)=WoT.
// ---------------------------------------------------------------------------
__global__ __launch_bounds__(256) void prep_kernel(
    const float* __restrict__ Ws, const float* __restrict__ bs,
    const float* __restrict__ Wa, const float* __restrict__ ba,
    const float* __restrict__ Wts, const float* __restrict__ bts,
    const float* __restrict__ Wta, const float* __restrict__ bta,
    const float* __restrict__ Wv, const float* __restrict__ Wo,
    unsigned short* __restrict__ Whi, unsigned short* __restrict__ Wlo,
    float* __restrict__ bcat)
{
    int idx = blockIdx.x * 256 + threadIdx.x;
    if (idx < NPACK8) {
        int n = idx >> 5;
        int k0 = (idx & 31) << 3;
        unsigned short h[8], l[8];
        #pragma unroll
        for (int t = 0; t < 8; t++) {
            int k = k0 + t;
            float v;
            if (n < 256) v = Wv[k * 256 + n];
            else if (n < 1024) {
                int j = n - 256;
                if (j < 256)      v = Ws [k * 256 + j];
                else if (j < 384) v = Wa [k * 128 + (j - 256)];
                else if (j < 640) v = Wts[k * 256 + (j - 384)];
                else              v = Wta[k * 128 + (j - 640)];
            } else v = Wo[k * 256 + (n - 1024)];
            split_bf16(v, &h[t], &l[t]);
        }
        uint4 hv, lv;
        hv.x = h[0] | ((unsigned)h[1] << 16); hv.y = h[2] | ((unsigned)h[3] << 16);
        hv.z = h[4] | ((unsigned)h[5] << 16); hv.w = h[6] | ((unsigned)h[7] << 16);
        lv.x = l[0] | ((unsigned)l[1] << 16); lv.y = l[2] | ((unsigned)l[3] << 16);
        lv.z = l[4] | ((unsigned)l[5] << 16); lv.w = l[6] | ((unsigned)l[7] << 16);
        *(uint4*)(Whi + n * 256 + k0) = hv;
        *(uint4*)(Wlo + n * 256 + k0) = lv;
    } else if (idx < NPACK8 + 768) {
        int j = idx - NPACK8;
        float v;
        if (j < 256)      v = bs[j];
        else if (j < 384) v = ba[j - 256];
        else if (j < 640) v = bts[j - 384];
        else              v = bta[j - 640];
        bcat[j] = v;
    }
}

// ---------------------------------------------------------------------------
// bf16x3 MFMA GEMM, dual problem-set.
// Tile (MSUB*64)(M) x 64(N), 256 thr = 4 waves, wave owns MSUB*16 rows.
// K=256 in 2 chunks of 128; B (hi+lo planes) async-staged per chunk into
// frag-order LDS (32 KB) via width-16 global_load_lds (LDS dest linear in
// lane order; the permutation rides on the per-lane GLOBAL address).
// AFMT=0: A is f32, inline register bf16x3 split.
// AFMT=1: A is pre-split hi/lo bf16 planes (lo at A + LEN*256); fragments
//         are direct 16B loads, prefetched BEFORE the staging barrier.
// mode: 0 = f32 row-major store; 1 = bf16 store into (head,pos,32ch) planes.
// ---------------------------------------------------------------------------
template <int MSUB, int AFMT>
__global__ __launch_bounds__(256) void gemm_mfma_dual(
    const float* __restrict__ A0,
    const unsigned short* __restrict__ B0hi, const unsigned short* __restrict__ B0lo,
    const float* __restrict__ bias0, void* __restrict__ C0, int N0, int mode0, int nbx0,
    const float* __restrict__ A1,
    const unsigned short* __restrict__ B1hi, const unsigned short* __restrict__ B1lo,
    const float* __restrict__ bias1, void* __restrict__ C1, int N1, int mode1)
{
    // frag-order LDS per chunk: [plane][kt(4)][nt(4)][lane(64)][8 bf16] = 32 KB
    __shared__ __align__(16) unsigned short Bf[2 * 4 * 4 * 64 * 8];
    const int tid = threadIdx.x;
    const int wave = tid >> 6, lane = tid & 63;
    int bx = blockIdx.x;
    const int by = blockIdx.y;

    const float* A;
    const unsigned short *Bhi, *Blo;
    const float* bias; void* C; int N, mode;
    if (bx < nbx0) {
        A = A0; Bhi = B0hi; Blo = B0lo;
        bias = bias0; C = C0; N = N0; mode = mode0;
    } else {
        bx -= nbx0;
        A = A1; Bhi = B1hi; Blo = B1lo;
        bias = bias1; C = C1; N = N1; mode = mode1;
    }

    const int lm = lane & 15;     // m within 16-tile / C column
    const int kq = lane >> 4;     // k-quad (0..3)
    const int m0 = by * (MSUB * 64) + wave * (MSUB * 16) + lm;
    const int ra = min(m0, LEN - 1);            // clamped A rows (loads in-bounds)
    const int rb = min(m0 + 16, LEN - 1);

    // AFMT=0 pointers (f32 A)
    const float* aP0 = A + (size_t)ra * 256 + kq * 8;
    const float* aP1 = A + (size_t)rb * 256 + kq * 8;
    // AFMT=1 pointers (pre-split bf16 planes; lo plane at +LEN*256)
    const unsigned short* Ah = (const unsigned short*)A;
    const unsigned short* ahP0 = Ah + (size_t)ra * 256 + kq * 8;
    const unsigned short* alP0 = Ah + (size_t)LEN * 256 + (size_t)ra * 256 + kq * 8;
    const unsigned short* ahP1 = Ah + (size_t)rb * 256 + kq * 8;
    const unsigned short* alP1 = Ah + (size_t)LEN * 256 + (size_t)rb * 256 + kq * 8;

    f32x4 acc[MSUB][4] = {};
    #pragma unroll
    for (int chunk = 0; chunk < 2; chunk++) {
        // async-stage chunk's B tile (both planes): 2048 slots x 16 B.
        // slot f = g*64 + lane, g = t*4 + wave encodes (pl,kt,nt).
        #pragma unroll
        for (int t = 0; t < 8; t++) {
            const int g  = t * 4 + wave;
            const int nt = g & 3, kt = (g >> 2) & 3, pl = g >> 4;
            const unsigned short* src = (pl ? Blo : Bhi)
                + (size_t)(bx * 64 + nt * 16 + (lane & 15)) * 256
                + chunk * 128 + kt * 32 + (lane >> 4) * 8;
            __builtin_amdgcn_global_load_lds(
                (AS1 void*)(uintptr_t)src,
                (AS3 void*)&Bf[(size_t)g * 64 * 8],
                16, 0, 0);
        }
        // AFMT=1: prefetch this chunk's A fragments while B staging is in flight
        bf16x8 pah[MSUB][4], pal[MSUB][4];
        if constexpr (AFMT == 1) {
            #pragma unroll
            for (int kt = 0; kt < 4; kt++) {
                const int ko = chunk * 128 + kt * 32;
                pah[0][kt] = *(const bf16x8*)(ahP0 + ko);
                pal[0][kt] = *(const bf16x8*)(alP0 + ko);
                if constexpr (MSUB == 2) {
                    pah[1][kt] = *(const bf16x8*)(ahP1 + ko);
                    pal[1][kt] = *(const bf16x8*)(alP1 + ko);
                }
            }
        }
        asm volatile("s_waitcnt vmcnt(0)" ::: "memory");
        __syncthreads();
        #pragma unroll
        for (int kt = 0; kt < 4; kt++) {
            const int ko = chunk * 128 + kt * 32;
            bf16x8 ah0, al0, ah1, al1;
            if constexpr (AFMT == 0) {
                splitA8(aP0 + ko, &ah0, &al0);
                if constexpr (MSUB == 2) splitA8(aP1 + ko, &ah1, &al1);
            } else {
                ah0 = pah[0][kt]; al0 = pal[0][kt];
                if constexpr (MSUB == 2) { ah1 = pah[1][kt]; al1 = pal[1][kt]; }
            }
            #pragma unroll
            for (int nt = 0; nt < 4; nt++) {
                const int fb = (kt * 4 + nt) * 64 + lane;
                bf16x8 bh = *(const bf16x8*)(&Bf[(size_t)fb * 8]);
                bf16x8 bl = *(const bf16x8*)(&Bf[(size_t)(fb + 1024) * 8]);
                acc[0][nt] = __builtin_amdgcn_mfma_f32_16x16x32_bf16(ah0, bh, acc[0][nt], 0, 0, 0);
                acc[0][nt] = __builtin_amdgcn_mfma_f32_16x16x32_bf16(ah0, bl, acc[0][nt], 0, 0, 0);
                acc[0][nt] = __builtin_amdgcn_mfma_f32_16x16x32_bf16(al0, bh, acc[0][nt], 0, 0, 0);
                if constexpr (MSUB == 2) {
                    acc[1][nt] = __builtin_amdgcn_mfma_f32_16x16x32_bf16(ah1, bh, acc[1][nt], 0, 0, 0);
                    acc[1][nt] = __builtin_amdgcn_mfma_f32_16x16x32_bf16(ah1, bl, acc[1][nt], 0, 0, 0);
                    acc[1][nt] = __builtin_amdgcn_mfma_f32_16x16x32_bf16(al1, bh, acc[1][nt], 0, 0, 0);
                }
            }
        }
        __syncthreads();
    }

    // C/D layout (verified m89/m91): col = lane&15, row = (lane>>4)*4 + reg
    const int col = bx * 64 + lm;
    #pragma unroll
    for (int sub = 0; sub < MSUB; sub++) {
        const int row0 = by * (MSUB * 64) + wave * (MSUB * 16) + sub * 16 + kq * 4;
        #pragma unroll
        for (int nt = 0; nt < 4; nt++) {
            int c = col + nt * 16;
            float bb = bias[c];
            #pragma unroll
            for (int r = 0; r < 4; r++) {
                int row = row0 + r;
                if (row < LEN) {
                    float v = acc[sub][nt][r] + bb;
                    if (mode) {
                        // value plane layout: head = c>>5, ch = c&31
                        ((unsigned short*)C)[(size_t)(c >> 5) * 8192 * 32
                                             + (size_t)row * 32 + (c & 31)] = rne_bf16(v);
                    } else {
                        ((float*)C)[(size_t)row * N + c] = v;
                    }
                }
            }
        }
    }
}

// ---------------------------------------------------------------------------
// Deformable sampling. One block per query (8160 blocks); 8 heads x 32 lanes.
// Value layout (head, pos, 32ch): the two x-adjacent corners of a y-row are
// CONTIGUOUS 128 B -> one gather covers both (8 lanes x 16 B).
// The query's proj row (768 f32 = 3 KB) is async-staged to LDS first (one
// coalesced width-16 global_load_lds burst, waves 0-2) replacing ~5 scattered
// scalar L2 loads per lane in phase 1.
// Phase 2 inner loop is packed: per dword (2 bf16 ch) one shl + one and
// produce an f32x2, accumulated with __builtin_elementwise_fma ->
// v_pk_fma_f32 (fused, bit-identical per-channel order to the scalar form).
// Epilogue writes attn PRE-SPLIT as hi/lo bf16 planes (lo at +LEN*256).
// ---------------------------------------------------------------------------
__global__ __launch_bounds__(256) void sample_kernel(
    const unsigned short* __restrict__ value,  // (8, 8192, 32) bf16 planes
    const float* __restrict__ proj,    // (8160, 768)
    const float* __restrict__ refp,    // (8160, 4, 2)
    const float* __restrict__ toff,    // (8160, 4, 2, 2)
    unsigned short* __restrict__ attn) // (2, 8160, 256) bf16 hi/lo planes
{
    const int q = blockIdx.x;
    const int tid = threadIdx.x;
    const int head = tid >> 5;
    const int lane = tid & 31;
    __shared__ __align__(16) float ps[768];
    __shared__ int2   s_row[8][32];
    __shared__ float4 s_w[8][32];

    // stage proj row: waves 0-2, 16 B/lane -> ps[wave*256 + lane*4 ..]
    if (tid < 192) {
        __builtin_amdgcn_global_load_lds(
            (AS1 void*)(uintptr_t)(proj + (size_t)q * 768 + tid * 4),
            (AS3 void*)&ps[(tid >> 6) * 256],
            16, 0, 0);
    }
    asm volatile("s_waitcnt vmcnt(0)" ::: "memory");
    __syncthreads();

    // ---- phase 1: per-point location, joint softmax, bilinear setup ----
    {
        const int i = lane;
        float logit, ox, oy, rx, ry;
        int l;
        if (i < 16) {
            l = i >> 2; int pt2 = i & 3;
            logit = ps[256 + head * 16 + i];
            ox = ps[head * 32 + l * 8 + pt2 * 2 + 0];
            oy = ps[head * 32 + l * 8 + pt2 * 2 + 1];
            rx = refp[q * 8 + l * 2 + 0];
            ry = refp[q * 8 + l * 2 + 1];
        } else {
            int j = i - 16; l = j >> 2;
            int tp = j & 3, tw = tp >> 1, nt = tp & 1;
            logit = ps[640 + head * 16 + j];
            ox = ps[384 + head * 32 + l * 8 + tw * 4 + nt * 2 + 0];
            oy = ps[384 + head * 32 + l * 8 + tw * 4 + nt * 2 + 1];
            rx = refp[q * 8 + l * 2 + 0] + toff[q * 16 + l * 4 + tw * 2 + 0];
            ry = refp[q * 8 + l * 2 + 1] + toff[q * 16 + l * 4 + tw * 2 + 1];
        }
        const int Wl = 48 >> l;
        const int Hgl = 128 >> l;
        const int st = 8192 - (8192 >> (2 * l));
        const float fW = (float)Wl, fHg = (float)Hgl;
        float x = (rx + ox / fW) * fW - 0.5f;
        float y = (ry + oy / fHg) * fHg - 0.5f;

        float mx = logit;
        #pragma unroll
        for (int off = 16; off > 0; off >>= 1)
            mx = fmaxf(mx, __shfl_xor(mx, off, 32));
        float e = expf(logit - mx);
        float s = e;
        #pragma unroll
        for (int off = 16; off > 0; off >>= 1)
            s += __shfl_xor(s, off, 32);
        float w = e / s;

        float fx = floorf(x), fy = floorf(y);
        float wx = x - fx, wy = y - fy;
        int x0 = (int)fx, y0 = (int)fy;
        int x1 = x0 + 1, y1 = y0 + 1;
        float mx0 = ((unsigned)x0 < (unsigned)Wl) ? 1.f : 0.f;
        float mx1 = ((unsigned)x1 < (unsigned)Wl) ? 1.f : 0.f;
        float my0 = ((unsigned)y0 < (unsigned)Hgl) ? 1.f : 0.f;
        float my1 = ((unsigned)y1 < (unsigned)Hgl) ? 1.f : 0.f;
        int cx0 = min(max(x0, 0), Wl - 1), cx1 = min(max(x1, 0), Wl - 1);
        int cy0 = min(max(y0, 0), Hgl - 1), cy1 = min(max(y1, 0), Hgl - 1);
        int xb = min(max(x0, 0), Wl - 2);
        float sx0 = 1.f - wx, sy0 = 1.f - wy;
        // per-half x weights (absorb clamping: each clamped corner lands on
        // whichever loaded half equals its clamped position)
        float aL = (cx0 == xb     ? sx0 * mx0 : 0.f) + (cx1 == xb     ? wx * mx1 : 0.f);
        float aR = (cx0 == xb + 1 ? sx0 * mx0 : 0.f) + (cx1 == xb + 1 ? wx * mx1 : 0.f);
        float by0 = sy0 * my0, by1 = wy * my1;
        int2 rr;   // BYTE offsets within a head plane (64 B per position)
        rr.x = (st + cy0 * Wl + xb) * 64;
        rr.y = (st + cy1 * Wl + xb) * 64;
        float4 ww;
        ww.x = w * aL * by0;   // y0 row, left half
        ww.y = w * aR * by0;   // y0 row, right half
        ww.z = w * aL * by1;   // y1 row, left half
        ww.w = w * aR * by1;   // y1 row, right half
        s_row[head][lane] = rr;
        s_w[head][lane] = ww;
    }
    // no barrier: s_row/s_w written and read by the same 32-lane half-wave

    // ---- phase 2: x-pair gathers, 4 points in flight per 32-lane group ----
    const int pt4  = lane >> 3;        // 0..3
    const int half = (lane >> 2) & 1;  // x-half within the 128B pair
    const int cg   = lane & 3;         // 8-channel group
    const char* vbase = (const char*)value + head * (8192 * 64) + half * 64 + cg * 16;
    f32x2 acc2[4] = {};                // acc2[k] = channels (2k, 2k+1)
    #pragma unroll
    for (int i = 0; i < 8; i++) {
        int pidx = (i << 2) | pt4;
        int2 rr = s_row[head][pidx];
        float4 ww = s_w[head][pidx];
        uint4 d0 = *(const uint4*)(vbase + rr.x);
        uint4 d1 = *(const uint4*)(vbase + rr.y);
        float w0 = half ? ww.y : ww.x;
        float w1 = half ? ww.w : ww.z;
        f32x2 w0v = {w0, w0}, w1v = {w1, w1};
        const unsigned* p0 = (const unsigned*)&d0;
        const unsigned* p1 = (const unsigned*)&d1;
        #pragma unroll
        for (int k = 0; k < 4; k++) {
            unsigned a = p0[k];
            f32x2 c;
            c[0] = __uint_as_float(a << 16);
            c[1] = __uint_as_float(a & 0xFFFF0000u);
            acc2[k] = __builtin_elementwise_fma(c, w0v, acc2[k]);
            unsigned b = p1[k];
            f32x2 e;
            e[0] = __uint_as_float(b << 16);
            e[1] = __uint_as_float(b & 0xFFFF0000u);
            acc2[k] = __builtin_elementwise_fma(e, w1v, acc2[k]);
        }
    }
    // butterfly: xor4 merges x-halves, xor8/16 merge the 4 points
    #pragma unroll
    for (int off = 4; off <= 16; off <<= 1)
        #pragma unroll
        for (int k = 0; k < 4; k++) {
            acc2[k][0] += __shfl_xor(acc2[k][0], off, 32);
            acc2[k][1] += __shfl_xor(acc2[k][1], off, 32);
        }

    if (lane < 4) {
        size_t o = (size_t)q * 256 + head * 32 + cg * 8;
        unsigned short h[8], l[8];
        #pragma unroll
        for (int k = 0; k < 4; k++) {
            split_bf16(acc2[k][0], &h[2 * k], &l[2 * k]);
            split_bf16(acc2[k][1], &h[2 * k + 1], &l[2 * k + 1]);
        }
        uint4 hv, lv;
        hv.x = h[0] | ((unsigned)h[1] << 16); hv.y = h[2] | ((unsigned)h[3] << 16);
        hv.z = h[4] | ((unsigned)h[5] << 16); hv.w = h[6] | ((unsigned)h[7] << 16);
        lv.x = l[0] | ((unsigned)l[1] << 16); lv.y = l[2] | ((unsigned)l[3] << 16);
        lv.z = l[4] | ((unsigned)l[5] << 16); lv.w = l[6] | ((unsigned)l[7] << 16);
        *(uint4*)(attn + o) = hv;
        *(uint4*)(attn + (size_t)LEN * 256 + o) = lv;
    }
}

// ---------------------------------------------------------------------------
extern "C" void kernel_launch(void* const* d_in, const int* in_sizes, int n_in,
                              void* d_out, int out_size, void* d_ws, size_t ws_size,
                              hipStream_t stream)
{
    const float* query = (const float*)d_in[0];
    const float* refp  = (const float*)d_in[1];
    const float* toff  = (const float*)d_in[2];
    const float* inpf  = (const float*)d_in[3];
    const float* Wv  = (const float*)d_in[6];
    const float* bv  = (const float*)d_in[7];
    const float* Ws_ = (const float*)d_in[8];
    const float* bs_ = (const float*)d_in[9];
    const float* Wa  = (const float*)d_in[10];
    const float* ba  = (const float*)d_in[11];
    const float* Wts = (const float*)d_in[12];
    const float* bts = (const float*)d_in[13];
    const float* Wta = (const float*)d_in[14];
    const float* bta = (const float*)d_in[15];
    const float* Wo  = (const float*)d_in[16];
    const float* bo  = (const float*)d_in[17];
    float* out = (float*)d_out;

    // workspace layout (~39 MB)
    unsigned short* value_bf = (unsigned short*)d_ws;          // 8 x 8192 x 32 bf16 planes
    float* proj = (float*)(value_bf + (size_t)8 * 8192 * 32);  // 8160*768 f32
    unsigned short* attn_hl = (unsigned short*)(proj + (size_t)LEN * 768); // 2 x 8160*256 bf16
    unsigned short* Whi = attn_hl + (size_t)2 * LEN * 256;     // 1280*256
    unsigned short* Wlo = Whi + 1280 * 256;
    float* bcat = (float*)(Wlo + 1280 * 256);                  // 768

    prep_kernel<<<164, 256, 0, stream>>>(Ws_, bs_, Wa, ba, Wts, bts, Wta, bta,
                                         Wv, Wo, Whi, Wlo, bcat);
    // value(bf16 planes) = inpf @ Wv + bv (bx 0..3) ||
    // proj(f32) = query @ Bcat + bcat (bx 4..15); grid (16, 64) = 1024 blocks
    gemm_mfma_dual<2, 0><<<dim3(16, 64), 256, 0, stream>>>(
        inpf, Whi, Wlo, bv, value_bf, 256, 1, 4,
        query, Whi + 256 * 256, Wlo + 256 * 256, bcat, proj, 768, 0);
    // deformable attention core -> attn (pre-split bf16 hi/lo planes)
    sample_kernel<<<LEN, 256, 0, stream>>>(value_bf, proj, refp, toff, attn_hl);
    // out(f32) = attn @ Wo + bo; 64-row tiles, grid (4, 128) = 512 blocks;
    // A = pre-split planes (AFMT=1)
    gemm_mfma_dual<1, 1><<<dim3(4, 128), 256, 0, stream>>>(
        (const float*)attn_hl, Whi + 1024 * 256, Wlo + 1024 * 256, bo, out, 256, 0, 4,
        (const float*)attn_hl, Whi + 1024 * 256, Wlo + 1024 * 256, bo, out, 256, 0);
}

// Round 4
// 167.763 us; speedup vs baseline: 1.0742x; 1.0100x over previous
//
#include <hip/hip_runtime.h>

// Problem constants (hard-coded from reference: SHAPES fixed at trace time)
// Level l: W=48>>l, Hgrid=128>>l, start = 8192 - (8192 >> (2*l)); LEN=8160.

#define LEN 8160
#define NPACK8 (1280 * 256 / 8)      // 40,960 (8-elem pack units)

#define AS1 __attribute__((address_space(1)))
#define AS3 __attribute__((address_space(3)))

typedef __attribute__((ext_vector_type(8))) short bf16x8;
typedef __attribute__((ext_vector_type(8))) unsigned short u16x8;
typedef __attribute__((ext_vector_type(4))) float f32x4;
typedef __attribute__((ext_vector_type(2))) float f32x2;

__device__ __forceinline__ unsigned short rne_bf16(float v)
{
    unsigned u = __float_as_uint(v);
    return (unsigned short)((u + 0x7FFFu + ((u >> 16) & 1u)) >> 16);
}

// Round-to-nearest-even split of fp32 into hi+lo bf16 (bf16x3 GEMM trick).
__device__ __forceinline__ void split_bf16(float v, unsigned short* hi, unsigned short* lo)
{
    unsigned u = __float_as_uint(v);
    unsigned r = (u + 0x7FFFu + ((u >> 16) & 1u)) & 0xFFFF0000u;
    float hif = __uint_as_float(r);
    float lof = v - hif;
    unsigned ul = __float_as_uint(lof);
    unsigned rl = (ul + 0x7FFFu + ((ul >> 16) & 1u)) >> 16;
    *hi = (unsigned short)(r >> 16);
    *lo = (unsigned short)rl;
}

__device__ __forceinline__ float bf2f(unsigned short s)
{
    return __uint_as_float(((unsigned)s) << 16);
}

// Inline split of 8 consecutive f32 A elements into hi/lo bf16x8 fragments.
__device__ __forceinline__ void splitA8(const float* a, bf16x8* hi, bf16x8* lo)
{
    float4 x = *(const float4*)a;
    float4 y = *(const float4*)(a + 4);
    unsigned short h[8], l[8];
    split_bf16(x.x, &h[0], &l[0]); split_bf16(x.y, &h[1], &l[1]);
    split_bf16(x.z, &h[2], &l[2]); split_bf16(x.w, &h[3], &l[3]);
    split_bf16(y.x, &h[4], &l[4]); split_bf16(y.y, &h[5], &l[5]);
    split_bf16(y.z, &h[6], &l[6]); split_bf16(y.w, &h[7], &l[7]);
    bf16x8 hv, lv;
    #pragma unroll
    for (int i = 0; i < 8; i++) { hv[i] = (short)h[i]; lv[i] = (short)l[i]; }
    *hi = hv; *lo = lv;
}

// ---------------------------------------------------------------------------
// prep: pack all weights transposed (B^T[n][k]) into hi/lo bf16 planes +
// concat bias. Row space: [0,256)=WvT [256,1024)=BcatT [1024,1280)=WoT.
// ---------------------------------------------------------------------------
__global__ __launch_bounds__(256) void prep_kernel(
    const float* __restrict__ Ws, const float* __restrict__ bs,
    const float* __restrict__ Wa, const float* __restrict__ ba,
    const float* __restrict__ Wts, const float* __restrict__ bts,
    const float* __restrict__ Wta, const float* __restrict__ bta,
    const float* __restrict__ Wv, const float* __restrict__ Wo,
    unsigned short* __restrict__ Whi, unsigned short* __restrict__ Wlo,
    float* __restrict__ bcat)
{
    int idx = blockIdx.x * 256 + threadIdx.x;
    if (idx < NPACK8) {
        int n = idx >> 5;
        int k0 = (idx & 31) << 3;
        unsigned short h[8], l[8];
        #pragma unroll
        for (int t = 0; t < 8; t++) {
            int k = k0 + t;
            float v;
            if (n < 256) v = Wv[k * 256 + n];
            else if (n < 1024) {
                int j = n - 256;
                if (j < 256)      v = Ws [k * 256 + j];
                else if (j < 384) v = Wa [k * 128 + (j - 256)];
                else if (j < 640) v = Wts[k * 256 + (j - 384)];
                else              v = Wta[k * 128 + (j - 640)];
            } else v = Wo[k * 256 + (n - 1024)];
            split_bf16(v, &h[t], &l[t]);
        }
        uint4 hv, lv;
        hv.x = h[0] | ((unsigned)h[1] << 16); hv.y = h[2] | ((unsigned)h[3] << 16);
        hv.z = h[4] | ((unsigned)h[5] << 16); hv.w = h[6] | ((unsigned)h[7] << 16);
        lv.x = l[0] | ((unsigned)l[1] << 16); lv.y = l[2] | ((unsigned)l[3] << 16);
        lv.z = l[4] | ((unsigned)l[5] << 16); lv.w = l[6] | ((unsigned)l[7] << 16);
        *(uint4*)(Whi + n * 256 + k0) = hv;
        *(uint4*)(Wlo + n * 256 + k0) = lv;
    } else if (idx < NPACK8 + 768) {
        int j = idx - NPACK8;
        float v;
        if (j < 256)      v = bs[j];
        else if (j < 384) v = ba[j - 256];
        else if (j < 640) v = bts[j - 384];
        else              v = bta[j - 640];
        bcat[j] = v;
    }
}

// ---------------------------------------------------------------------------
// bf16x3 MFMA GEMM, dual problem-set.
// Tile (MSUB*64)(M) x (NT*16)(N), 256 thr = 4 waves, wave owns MSUB*16 rows
// and all NT*16 cols. K=256 in 2 chunks of 128; B (hi+lo planes) async-staged
// per chunk into frag-order LDS via width-16 global_load_lds (LDS dest linear
// in lane order; the permutation rides on the per-lane GLOBAL address).
// NT=8 -> 64 KB LDS (2 blocks/CU), NT=4 -> 32 KB.
// Wider NT cuts A re-reads AND the redundant A split VALU by the same factor.
// AFMT=0: A is f32, inline register bf16x3 split.
// AFMT=1: A is pre-split hi/lo bf16 planes (lo at A + LEN*256); fragments
//         are direct 16B loads, prefetched BEFORE the staging barrier.
// mode: 0 = f32 row-major store; 1 = bf16 store into (head,pos,32ch) planes.
// ---------------------------------------------------------------------------
template <int MSUB, int AFMT, int NT>
__global__ __launch_bounds__(256) void gemm_mfma_dual(
    const float* __restrict__ A0,
    const unsigned short* __restrict__ B0hi, const unsigned short* __restrict__ B0lo,
    const float* __restrict__ bias0, void* __restrict__ C0, int N0, int mode0, int nbx0,
    const float* __restrict__ A1,
    const unsigned short* __restrict__ B1hi, const unsigned short* __restrict__ B1lo,
    const float* __restrict__ bias1, void* __restrict__ C1, int N1, int mode1)
{
    // frag-order LDS per chunk: [plane][kt(4)][nt(NT)][lane(64)][8 bf16]
    __shared__ __align__(16) unsigned short Bf[2 * 4 * NT * 64 * 8];
    const int tid = threadIdx.x;
    const int wave = tid >> 6, lane = tid & 63;
    int bx = blockIdx.x;
    const int by = blockIdx.y;

    const float* A;
    const unsigned short *Bhi, *Blo;
    const float* bias; void* C; int N, mode;
    if (bx < nbx0) {
        A = A0; Bhi = B0hi; Blo = B0lo;
        bias = bias0; C = C0; N = N0; mode = mode0;
    } else {
        bx -= nbx0;
        A = A1; Bhi = B1hi; Blo = B1lo;
        bias = bias1; C = C1; N = N1; mode = mode1;
    }

    const int lm = lane & 15;     // m within 16-tile / C column
    const int kq = lane >> 4;     // k-quad (0..3)
    const int m0 = by * (MSUB * 64) + wave * (MSUB * 16) + lm;
    const int ra = min(m0, LEN - 1);            // clamped A rows (loads in-bounds)
    const int rb = min(m0 + 16, LEN - 1);

    // AFMT=0 pointers (f32 A)
    const float* aP0 = A + (size_t)ra * 256 + kq * 8;
    const float* aP1 = A + (size_t)rb * 256 + kq * 8;
    // AFMT=1 pointers (pre-split bf16 planes; lo plane at +LEN*256)
    const unsigned short* Ah = (const unsigned short*)A;
    const unsigned short* ahP0 = Ah + (size_t)ra * 256 + kq * 8;
    const unsigned short* alP0 = Ah + (size_t)LEN * 256 + (size_t)ra * 256 + kq * 8;
    const unsigned short* ahP1 = Ah + (size_t)rb * 256 + kq * 8;
    const unsigned short* alP1 = Ah + (size_t)LEN * 256 + (size_t)rb * 256 + kq * 8;

    f32x4 acc[MSUB][NT] = {};
    #pragma unroll
    for (int chunk = 0; chunk < 2; chunk++) {
        // async-stage chunk's B tile (both planes): 2*4*NT*64 slots x 16 B.
        // slot f = g*64 + lane, g = t*4 + wave encodes (pl,kt,nt).
        #pragma unroll
        for (int t = 0; t < 2 * NT; t++) {
            const int g  = t * 4 + wave;
            const int nt = g % NT, kt = (g / NT) & 3, pl = g / (NT * 4);
            const unsigned short* src = (pl ? Blo : Bhi)
                + (size_t)(bx * (NT * 16) + nt * 16 + (lane & 15)) * 256
                + chunk * 128 + kt * 32 + (lane >> 4) * 8;
            __builtin_amdgcn_global_load_lds(
                (AS1 void*)(uintptr_t)src,
                (AS3 void*)&Bf[(size_t)g * 64 * 8],
                16, 0, 0);
        }
        // AFMT=1: prefetch this chunk's A fragments while B staging is in flight
        bf16x8 pah[MSUB][4], pal[MSUB][4];
        if constexpr (AFMT == 1) {
            #pragma unroll
            for (int kt = 0; kt < 4; kt++) {
                const int ko = chunk * 128 + kt * 32;
                pah[0][kt] = *(const bf16x8*)(ahP0 + ko);
                pal[0][kt] = *(const bf16x8*)(alP0 + ko);
                if constexpr (MSUB == 2) {
                    pah[1][kt] = *(const bf16x8*)(ahP1 + ko);
                    pal[1][kt] = *(const bf16x8*)(alP1 + ko);
                }
            }
        }
        asm volatile("s_waitcnt vmcnt(0)" ::: "memory");
        __syncthreads();
        #pragma unroll
        for (int kt = 0; kt < 4; kt++) {
            const int ko = chunk * 128 + kt * 32;
            bf16x8 ah0, al0, ah1, al1;
            if constexpr (AFMT == 0) {
                splitA8(aP0 + ko, &ah0, &al0);
                if constexpr (MSUB == 2) splitA8(aP1 + ko, &ah1, &al1);
            } else {
                ah0 = pah[0][kt]; al0 = pal[0][kt];
                if constexpr (MSUB == 2) { ah1 = pah[1][kt]; al1 = pal[1][kt]; }
            }
            #pragma unroll
            for (int nt = 0; nt < NT; nt++) {
                const int fb = (kt * NT + nt) * 64 + lane;
                bf16x8 bh = *(const bf16x8*)(&Bf[(size_t)fb * 8]);
                bf16x8 bl = *(const bf16x8*)(&Bf[(size_t)(fb + 4 * NT * 64) * 8]);
                acc[0][nt] = __builtin_amdgcn_mfma_f32_16x16x32_bf16(ah0, bh, acc[0][nt], 0, 0, 0);
                acc[0][nt] = __builtin_amdgcn_mfma_f32_16x16x32_bf16(ah0, bl, acc[0][nt], 0, 0, 0);
                acc[0][nt] = __builtin_amdgcn_mfma_f32_16x16x32_bf16(al0, bh, acc[0][nt], 0, 0, 0);
                if constexpr (MSUB == 2) {
                    acc[1][nt] = __builtin_amdgcn_mfma_f32_16x16x32_bf16(ah1, bh, acc[1][nt], 0, 0, 0);
                    acc[1][nt] = __builtin_amdgcn_mfma_f32_16x16x32_bf16(ah1, bl, acc[1][nt], 0, 0, 0);
                    acc[1][nt] = __builtin_amdgcn_mfma_f32_16x16x32_bf16(al1, bh, acc[1][nt], 0, 0, 0);
                }
            }
        }
        __syncthreads();
    }

    // C/D layout (verified m89/m91): col = lane&15, row = (lane>>4)*4 + reg
    const int col = bx * (NT * 16) + lm;
    #pragma unroll
    for (int sub = 0; sub < MSUB; sub++) {
        const int row0 = by * (MSUB * 64) + wave * (MSUB * 16) + sub * 16 + kq * 4;
        #pragma unroll
        for (int nt = 0; nt < NT; nt++) {
            int c = col + nt * 16;
            float bb = bias[c];
            #pragma unroll
            for (int r = 0; r < 4; r++) {
                int row = row0 + r;
                if (row < LEN) {
                    float v = acc[sub][nt][r] + bb;
                    if (mode) {
                        // value plane layout: head = c>>5, ch = c&31
                        ((unsigned short*)C)[(size_t)(c >> 5) * 8192 * 32
                                             + (size_t)row * 32 + (c & 31)] = rne_bf16(v);
                    } else {
                        ((float*)C)[(size_t)row * N + c] = v;
                    }
                }
            }
        }
    }
}

// ---------------------------------------------------------------------------
// Deformable sampling. One block per query (8160 blocks); 8 heads x 32 lanes.
// Value layout (head, pos, 32ch): the two x-adjacent corners of a y-row are
// CONTIGUOUS 128 B -> one gather covers both (8 lanes x 16 B).
// The query's proj row (768 f32 = 3 KB) is async-staged to LDS first (one
// coalesced width-16 global_load_lds burst, waves 0-2).
// Phase 2 inner loop is packed: per dword (2 bf16 ch) one shl + one and
// produce an f32x2, accumulated with __builtin_elementwise_fma ->
// v_pk_fma_f32 (fused, bit-identical per-channel order to the scalar form).
// Epilogue writes attn PRE-SPLIT as hi/lo bf16 planes (lo at +LEN*256).
// ---------------------------------------------------------------------------
__global__ __launch_bounds__(256) void sample_kernel(
    const unsigned short* __restrict__ value,  // (8, 8192, 32) bf16 planes
    const float* __restrict__ proj,    // (8160, 768)
    const float* __restrict__ refp,    // (8160, 4, 2)
    const float* __restrict__ toff,    // (8160, 4, 2, 2)
    unsigned short* __restrict__ attn) // (2, 8160, 256) bf16 hi/lo planes
{
    const int q = blockIdx.x;
    const int tid = threadIdx.x;
    const int head = tid >> 5;
    const int lane = tid & 31;
    __shared__ __align__(16) float ps[768];
    __shared__ int2   s_row[8][32];
    __shared__ float4 s_w[8][32];

    // stage proj row: waves 0-2, 16 B/lane -> ps[wave*256 + lane*4 ..]
    if (tid < 192) {
        __builtin_amdgcn_global_load_lds(
            (AS1 void*)(uintptr_t)(proj + (size_t)q * 768 + tid * 4),
            (AS3 void*)&ps[(tid >> 6) * 256],
            16, 0, 0);
    }
    asm volatile("s_waitcnt vmcnt(0)" ::: "memory");
    __syncthreads();

    // ---- phase 1: per-point location, joint softmax, bilinear setup ----
    {
        const int i = lane;
        float logit, ox, oy, rx, ry;
        int l;
        if (i < 16) {
            l = i >> 2; int pt2 = i & 3;
            logit = ps[256 + head * 16 + i];
            ox = ps[head * 32 + l * 8 + pt2 * 2 + 0];
            oy = ps[head * 32 + l * 8 + pt2 * 2 + 1];
            rx = refp[q * 8 + l * 2 + 0];
            ry = refp[q * 8 + l * 2 + 1];
        } else {
            int j = i - 16; l = j >> 2;
            int tp = j & 3, tw = tp >> 1, nt = tp & 1;
            logit = ps[640 + head * 16 + j];
            ox = ps[384 + head * 32 + l * 8 + tw * 4 + nt * 2 + 0];
            oy = ps[384 + head * 32 + l * 8 + tw * 4 + nt * 2 + 1];
            rx = refp[q * 8 + l * 2 + 0] + toff[q * 16 + l * 4 + tw * 2 + 0];
            ry = refp[q * 8 + l * 2 + 1] + toff[q * 16 + l * 4 + tw * 2 + 1];
        }
        const int Wl = 48 >> l;
        const int Hgl = 128 >> l;
        const int st = 8192 - (8192 >> (2 * l));
        const float fW = (float)Wl, fHg = (float)Hgl;
        float x = (rx + ox / fW) * fW - 0.5f;
        float y = (ry + oy / fHg) * fHg - 0.5f;

        float mx = logit;
        #pragma unroll
        for (int off = 16; off > 0; off >>= 1)
            mx = fmaxf(mx, __shfl_xor(mx, off, 32));
        float e = expf(logit - mx);
        float s = e;
        #pragma unroll
        for (int off = 16; off > 0; off >>= 1)
            s += __shfl_xor(s, off, 32);
        float w = e / s;

        float fx = floorf(x), fy = floorf(y);
        float wx = x - fx, wy = y - fy;
        int x0 = (int)fx, y0 = (int)fy;
        int x1 = x0 + 1, y1 = y0 + 1;
        float mx0 = ((unsigned)x0 < (unsigned)Wl) ? 1.f : 0.f;
        float mx1 = ((unsigned)x1 < (unsigned)Wl) ? 1.f : 0.f;
        float my0 = ((unsigned)y0 < (unsigned)Hgl) ? 1.f : 0.f;
        float my1 = ((unsigned)y1 < (unsigned)Hgl) ? 1.f : 0.f;
        int cx0 = min(max(x0, 0), Wl - 1), cx1 = min(max(x1, 0), Wl - 1);
        int cy0 = min(max(y0, 0), Hgl - 1), cy1 = min(max(y1, 0), Hgl - 1);
        int xb = min(max(x0, 0), Wl - 2);
        float sx0 = 1.f - wx, sy0 = 1.f - wy;
        // per-half x weights (absorb clamping: each clamped corner lands on
        // whichever loaded half equals its clamped position)
        float aL = (cx0 == xb     ? sx0 * mx0 : 0.f) + (cx1 == xb     ? wx * mx1 : 0.f);
        float aR = (cx0 == xb + 1 ? sx0 * mx0 : 0.f) + (cx1 == xb + 1 ? wx * mx1 : 0.f);
        float by0 = sy0 * my0, by1 = wy * my1;
        int2 rr;   // BYTE offsets within a head plane (64 B per position)
        rr.x = (st + cy0 * Wl + xb) * 64;
        rr.y = (st + cy1 * Wl + xb) * 64;
        float4 ww;
        ww.x = w * aL * by0;   // y0 row, left half
        ww.y = w * aR * by0;   // y0 row, right half
        ww.z = w * aL * by1;   // y1 row, left half
        ww.w = w * aR * by1;   // y1 row, right half
        s_row[head][lane] = rr;
        s_w[head][lane] = ww;
    }
    // no barrier: s_row/s_w written and read by the same 32-lane half-wave

    // ---- phase 2: x-pair gathers, 4 points in flight per 32-lane group ----
    const int pt4  = lane >> 3;        // 0..3
    const int half = (lane >> 2) & 1;  // x-half within the 128B pair
    const int cg   = lane & 3;         // 8-channel group
    const char* vbase = (const char*)value + head * (8192 * 64) + half * 64 + cg * 16;
    f32x2 acc2[4] = {};                // acc2[k] = channels (2k, 2k+1)
    #pragma unroll
    for (int i = 0; i < 8; i++) {
        int pidx = (i << 2) | pt4;
        int2 rr = s_row[head][pidx];
        float4 ww = s_w[head][pidx];
        uint4 d0 = *(const uint4*)(vbase + rr.x);
        uint4 d1 = *(const uint4*)(vbase + rr.y);
        float w0 = half ? ww.y : ww.x;
        float w1 = half ? ww.w : ww.z;
        f32x2 w0v = {w0, w0}, w1v = {w1, w1};
        const unsigned* p0 = (const unsigned*)&d0;
        const unsigned* p1 = (const unsigned*)&d1;
        #pragma unroll
        for (int k = 0; k < 4; k++) {
            unsigned a = p0[k];
            f32x2 c;
            c[0] = __uint_as_float(a << 16);
            c[1] = __uint_as_float(a & 0xFFFF0000u);
            acc2[k] = __builtin_elementwise_fma(c, w0v, acc2[k]);
            unsigned b = p1[k];
            f32x2 e;
            e[0] = __uint_as_float(b << 16);
            e[1] = __uint_as_float(b & 0xFFFF0000u);
            acc2[k] = __builtin_elementwise_fma(e, w1v, acc2[k]);
        }
    }
    // butterfly: xor4 merges x-halves, xor8/16 merge the 4 points
    #pragma unroll
    for (int off = 4; off <= 16; off <<= 1)
        #pragma unroll
        for (int k = 0; k < 4; k++) {
            acc2[k][0] += __shfl_xor(acc2[k][0], off, 32);
            acc2[k][1] += __shfl_xor(acc2[k][1], off, 32);
        }

    if (lane < 4) {
        size_t o = (size_t)q * 256 + head * 32 + cg * 8;
        unsigned short h[8], l[8];
        #pragma unroll
        for (int k = 0; k < 4; k++) {
            split_bf16(acc2[k][0], &h[2 * k], &l[2 * k]);
            split_bf16(acc2[k][1], &h[2 * k + 1], &l[2 * k + 1]);
        }
        uint4 hv, lv;
        hv.x = h[0] | ((unsigned)h[1] << 16); hv.y = h[2] | ((unsigned)h[3] << 16);
        hv.z = h[4] | ((unsigned)h[5] << 16); hv.w = h[6] | ((unsigned)h[7] << 16);
        lv.x = l[0] | ((unsigned)l[1] << 16); lv.y = l[2] | ((unsigned)l[3] << 16);
        lv.z = l[4] | ((unsigned)l[5] << 16); lv.w = l[6] | ((unsigned)l[7] << 16);
        *(uint4*)(attn + o) = hv;
        *(uint4*)(attn + (size_t)LEN * 256 + o) = lv;
    }
}

// ---------------------------------------------------------------------------
extern "C" void kernel_launch(void* const* d_in, const int* in_sizes, int n_in,
                              void* d_out, int out_size, void* d_ws, size_t ws_size,
                              hipStream_t stream)
{
    const float* query = (const float*)d_in[0];
    const float* refp  = (const float*)d_in[1];
    const float* toff  = (const float*)d_in[2];
    const float* inpf  = (const float*)d_in[3];
    const float* Wv  = (const float*)d_in[6];
    const float* bv  = (const float*)d_in[7];
    const float* Ws_ = (const float*)d_in[8];
    const float* bs_ = (const float*)d_in[9];
    const float* Wa  = (const float*)d_in[10];
    const float* ba  = (const float*)d_in[11];
    const float* Wts = (const float*)d_in[12];
    const float* bts = (const float*)d_in[13];
    const float* Wta = (const float*)d_in[14];
    const float* bta = (const float*)d_in[15];
    const float* Wo  = (const float*)d_in[16];
    const float* bo  = (const float*)d_in[17];
    float* out = (float*)d_out;

    // workspace layout (~39 MB)
    unsigned short* value_bf = (unsigned short*)d_ws;          // 8 x 8192 x 32 bf16 planes
    float* proj = (float*)(value_bf + (size_t)8 * 8192 * 32);  // 8160*768 f32
    unsigned short* attn_hl = (unsigned short*)(proj + (size_t)LEN * 768); // 2 x 8160*256 bf16
    unsigned short* Whi = attn_hl + (size_t)2 * LEN * 256;     // 1280*256
    unsigned short* Wlo = Whi + 1280 * 256;
    float* bcat = (float*)(Wlo + 1280 * 256);                  // 768

    prep_kernel<<<164, 256, 0, stream>>>(Ws_, bs_, Wa, ba, Wts, bts, Wta, bta,
                                         Wv, Wo, Whi, Wlo, bcat);
    // value(bf16 planes) = inpf @ Wv + bv (bx 0..1, N=256 = 2x128) ||
    // proj(f32) = query @ Bcat + bcat (bx 2..7, N=768 = 6x128)
    // grid (8, 64) = 512 blocks, 128x128 tiles, 64 KB LDS (2 blocks/CU)
    gemm_mfma_dual<2, 0, 8><<<dim3(8, 64), 256, 0, stream>>>(
        inpf, Whi, Wlo, bv, value_bf, 256, 1, 2,
        query, Whi + 256 * 256, Wlo + 256 * 256, bcat, proj, 768, 0);
    // deformable attention core -> attn (pre-split bf16 hi/lo planes)
    sample_kernel<<<LEN, 256, 0, stream>>>(value_bf, proj, refp, toff, attn_hl);
    // out(f32) = attn @ Wo + bo; 64-row x 64-col tiles, grid (4, 128) = 512
    // blocks; A = pre-split planes (AFMT=1)
    gemm_mfma_dual<1, 1, 4><<<dim3(4, 128), 256, 0, stream>>>(
        (const float*)attn_hl, Whi + 1024 * 256, Wlo + 1024 * 256, bo, out, 256, 0, 4,
        (const float*)attn_hl, Whi + 1024 * 256, Wlo + 1024 * 256, bo, out, 256, 0);
}